// Round 4
// baseline (465.949 us; speedup 1.0000x reference)
//
#include <hip/hip_runtime.h>
#include <hip/hip_bf16.h>
#include <stdint.h>

typedef unsigned int uint;
typedef unsigned short ushort;

#define NB 4
#define SL 4096
#define EMB 1024
#define NH 16
#define DH 64
#define WIN 256
#define OVL 32
#define NW 16
#define NTOK (NB * SL)

typedef __attribute__((ext_vector_type(8))) short short8;   // 8 bf16 = 4 VGPR
typedef __attribute__((ext_vector_type(4))) float float4v;  // 4 fp32 acc

#define AS1 __attribute__((address_space(1)))
#define AS3 __attribute__((address_space(3)))

// bf16 helpers
__device__ __forceinline__ float bf2f(ushort s) { return __uint_as_float((uint)s << 16); }
__device__ __forceinline__ ushort f2bf(float x) {  // round-to-nearest-even
  uint u = __float_as_uint(x);
  u += 0x7fffu + ((u >> 16) & 1u);
  return (ushort)(u >> 16);
}
__device__ __forceinline__ uint packbf(float a, float b) {
  return (uint)f2bf(a) | ((uint)f2bf(b) << 16);
}

// ---------------------------------------------------------------------------
// Kernel 1: MFMA QKV projection (unchanged from round 3).
// ---------------------------------------------------------------------------
__global__ __launch_bounds__(256) void qkv_proj_mfma(
    const float* __restrict__ qin, const float* __restrict__ kin,
    const float* __restrict__ vin,
    const float* __restrict__ Wq, const float* __restrict__ Wk,
    const float* __restrict__ Wv,
    ushort* __restrict__ qo, ushort* __restrict__ ko, ushort* __restrict__ vo) {
  __shared__ alignas(16) ushort sx[256 * 72];  // x tile [tok][d], then out [tok][e]
  __shared__ alignas(16) ushort sw[64 * 72];   // W [e][d]
  const int t = threadIdx.x;
  const int wid = t >> 6, lane = t & 63, quad = lane >> 4, l16 = lane & 15;
  const int p = blockIdx.z, h = blockIdx.y;
  const int tok0 = blockIdx.x * 256;

  const float* src = (p == 0) ? qin : ((p == 1) ? kin : vin);
  const float* W   = (p == 0) ? Wq  : ((p == 1) ? Wk  : Wv);
  ushort* dst      = (p == 0) ? qo  : ((p == 1) ? ko  : vo);

  for (int i = t; i < 1024; i += 256) {
    int e = i >> 4, c4 = i & 15;
    float4 f = *(const float4*)(W + e * 64 + c4 * 4);
    uint2 u;
    u.x = packbf(f.x, f.y);
    u.y = packbf(f.z, f.w);
    *(uint2*)&sw[e * 72 + c4 * 4] = u;
  }
  for (int i = t; i < 4096; i += 256) {
    int tok = i >> 4, c4 = i & 15;
    float4 f = *(const float4*)(src + (size_t)(tok0 + tok) * EMB + h * DH + c4 * 4);
    uint2 u;
    u.x = packbf(f.x, f.y);
    u.y = packbf(f.z, f.w);
    *(uint2*)&sx[tok * 72 + c4 * 4] = u;
  }
  __syncthreads();

  short8 wa[4][2], xb[4][2];
#pragma unroll
  for (int mt = 0; mt < 4; ++mt)
#pragma unroll
    for (int kh = 0; kh < 2; ++kh)
      wa[mt][kh] = *(const short8*)&sw[(mt * 16 + l16) * 72 + kh * 32 + quad * 8];
#pragma unroll
  for (int nt = 0; nt < 4; ++nt)
#pragma unroll
    for (int kh = 0; kh < 2; ++kh)
      xb[nt][kh] = *(const short8*)&sx[(wid * 64 + nt * 16 + l16) * 72 + kh * 32 + quad * 8];

  float4v acc[4][4];
#pragma unroll
  for (int i = 0; i < 4; ++i)
#pragma unroll
    for (int j = 0; j < 4; ++j) acc[i][j] = (float4v){0.f, 0.f, 0.f, 0.f};
#pragma unroll
  for (int kh = 0; kh < 2; ++kh)
#pragma unroll
    for (int mt = 0; mt < 4; ++mt)
#pragma unroll
      for (int nt = 0; nt < 4; ++nt)
        acc[mt][nt] = __builtin_amdgcn_mfma_f32_16x16x32_bf16(
            wa[mt][kh], xb[nt][kh], acc[mt][nt], 0, 0, 0);

  __syncthreads();
#pragma unroll
  for (int mt = 0; mt < 4; ++mt)
#pragma unroll
    for (int nt = 0; nt < 4; ++nt) {
      uint2 u;
      u.x = packbf(acc[mt][nt][0], acc[mt][nt][1]);
      u.y = packbf(acc[mt][nt][2], acc[mt][nt][3]);
      *(uint2*)&sx[(wid * 64 + nt * 16 + l16) * 72 + mt * 16 + quad * 4] = u;
    }
  __syncthreads();

  {
    const int tokg = tok0 + t;
    const int nb = tokg >> 12, l = tokg & 4095;
    uint4* orow = (uint4*)(dst + ((size_t)(nb * NH + h) * SL + l) * DH);
#pragma unroll
    for (int j = 0; j < 8; ++j) orow[j] = *(const uint4*)&sx[t * 72 + j * 8];
  }
}

// ---------------------------------------------------------------------------
// Kernel 2: S^T-formulation MFMA windowed attention, fixed-max softmax.
// Block = (n,w,h), 4 waves x 64 queries. S^T = K·Q^T (A=K rows, B=Q rows) so
// C-layout holds (key=quad*4+reg, q=l16): P packs to b64 LDS stores and PV is
// O^T = V^T·P^T. No online softmax: exp2 with per-query scale sc (0 for
// masked queries -> uniform, matching ref's constant -1e10 logits); invalid
// boundary keys zeroed only in edge chunks (wave-uniform kmask). lsum is a
// per-lane partial, reduced once at the end (shfl 16,32).
// ---------------------------------------------------------------------------
__global__ __launch_bounds__(256, 3) void attn_win_mfma(
    const ushort* __restrict__ qws, const ushort* __restrict__ kws,
    const ushort* __restrict__ vws, const int* __restrict__ mask,
    ushort* __restrict__ att) {
  __shared__ alignas(16) ushort sk[64 * 72];        // K chunk [key][d]
  __shared__ alignas(16) ushort svT[64 * 72];       // V chunk transposed [d][key]
  __shared__ alignas(16) ushort sp[4][64 * 40];     // per-wave P [q][key-half]

  const int t = threadIdx.x;
  const int wid = t >> 6, lane = t & 63, quad = lane >> 4, l16 = lane & 15;
  const int bid = blockIdx.x;
  const int h = bid & 15, w = (bid >> 4) & 15, nb = bid >> 8;
  const size_t headbase = (size_t)(nb * NH + h) * SL;
  const int q0 = w * WIN + wid * 64;  // first query row of this wave

  const float CSC = 0.18033688f;  // 0.125 * log2(e)
  // per-query scale: 0 for masked queries -> p=1 uniform (ref semantics)
  float sc[4];
#pragma unroll
  for (int qt = 0; qt < 4; ++qt)
    sc[qt] = mask[nb * SL + q0 + qt * 16 + l16] ? CSC : 0.f;

  // Q fragments (B operand: n=q=l16, k=d=quad*8+j)
  short8 qf[4][2];
#pragma unroll
  for (int qt = 0; qt < 4; ++qt)
#pragma unroll
    for (int kd = 0; kd < 2; ++kd)
      qf[qt][kd] = *(const short8*)(qws + (headbase + q0 + qt * 16 + l16) * DH +
                                    kd * 32 + quad * 8);

  float4v Of[4][4];  // [dt][qt], O^T C-layout: row=d, col=q
#pragma unroll
  for (int dt = 0; dt < 4; ++dt)
#pragma unroll
    for (int qt = 0; qt < 4; ++qt) Of[dt][qt] = (float4v){0.f, 0.f, 0.f, 0.f};
  float lsum[4] = {0.f, 0.f, 0.f, 0.f};

  ushort* spw = &sp[wid][0];
  const int gk0 = w * WIN - OVL;

  for (int c = 0; c < 5; ++c) {
    __syncthreads();
    const int cbase = gk0 + c * 64;
    // stage K [key][d] and V^T [d][key]
    for (int s = t; s < 512; s += 256) {
      int key = s & 63, dj = s >> 6;
      int gk = cbase + key;
      uint4 kq = make_uint4(0u, 0u, 0u, 0u);
      uint4 vq = make_uint4(0u, 0u, 0u, 0u);
      if ((unsigned)gk < (unsigned)SL) {
        kq = *(const uint4*)(kws + (headbase + gk) * DH + dj * 8);
        vq = *(const uint4*)(vws + (headbase + gk) * DH + dj * 8);
      }
      *(uint4*)&sk[key * 72 + dj * 8] = kq;
      svT[(dj * 8 + 0) * 72 + key] = (ushort)(vq.x & 0xffffu);
      svT[(dj * 8 + 1) * 72 + key] = (ushort)(vq.x >> 16);
      svT[(dj * 8 + 2) * 72 + key] = (ushort)(vq.y & 0xffffu);
      svT[(dj * 8 + 3) * 72 + key] = (ushort)(vq.y >> 16);
      svT[(dj * 8 + 4) * 72 + key] = (ushort)(vq.z & 0xffffu);
      svT[(dj * 8 + 5) * 72 + key] = (ushort)(vq.z >> 16);
      svT[(dj * 8 + 6) * 72 + key] = (ushort)(vq.w & 0xffffu);
      svT[(dj * 8 + 7) * 72 + key] = (ushort)(vq.w >> 16);
    }
    __syncthreads();

    const bool kmask = (cbase < 0) || (cbase + 64 > SL);

#pragma unroll
    for (int khk = 0; khk < 2; ++khk) {  // 32-key half
      // S^T = K·Q^T over this half: frags [ktr 2][qt 4]
      float4v Sf[2][4];
#pragma unroll
      for (int kt = 0; kt < 2; ++kt)
#pragma unroll
        for (int qt = 0; qt < 4; ++qt) Sf[kt][qt] = (float4v){0.f, 0.f, 0.f, 0.f};
#pragma unroll
      for (int kd = 0; kd < 2; ++kd) {
        short8 kf[2];
#pragma unroll
        for (int kt = 0; kt < 2; ++kt)
          kf[kt] = *(const short8*)&sk[(khk * 32 + kt * 16 + l16) * 72 +
                                       kd * 32 + quad * 8];
#pragma unroll
        for (int kt = 0; kt < 2; ++kt)
#pragma unroll
          for (int qt = 0; qt < 4; ++qt)
            Sf[kt][qt] = __builtin_amdgcn_mfma_f32_16x16x32_bf16(
                kf[kt], qf[qt][kd], Sf[kt][qt], 0, 0, 0);
      }

      // p = exp2(s*sc); zero invalid keys (edge chunks only); pack -> LDS
#pragma unroll
      for (int kt = 0; kt < 2; ++kt)
#pragma unroll
        for (int qt = 0; qt < 4; ++qt) {
          float p[4];
#pragma unroll
          for (int r = 0; r < 4; ++r)
            p[r] = exp2f(Sf[kt][qt][r] * sc[qt]);
          if (kmask) {
#pragma unroll
            for (int r = 0; r < 4; ++r) {
              const int gkey = cbase + khk * 32 + kt * 16 + quad * 4 + r;
              if ((unsigned)gkey >= (unsigned)SL) p[r] = 0.f;
            }
          }
          uint2 u;
          u.x = packbf(p[0], p[1]);
          u.y = packbf(p[2], p[3]);
          lsum[qt] += (bf2f((ushort)(u.x & 0xffffu)) + bf2f((ushort)(u.x >> 16))) +
                      (bf2f((ushort)(u.y & 0xffffu)) + bf2f((ushort)(u.y >> 16)));
          *(uint2*)&spw[(qt * 16 + l16) * 40 + kt * 16 + quad * 4] = u;
        }

      // O^T += V^T · P^T  (k = 32 keys of this half)
      short8 vf[4], pf[4];
#pragma unroll
      for (int dt = 0; dt < 4; ++dt)
        vf[dt] = *(const short8*)&svT[(dt * 16 + l16) * 72 + khk * 32 + quad * 8];
#pragma unroll
      for (int qt = 0; qt < 4; ++qt)
        pf[qt] = *(const short8*)&spw[(qt * 16 + l16) * 40 + quad * 8];
#pragma unroll
      for (int dt = 0; dt < 4; ++dt)
#pragma unroll
        for (int qt = 0; qt < 4; ++qt)
          Of[dt][qt] = __builtin_amdgcn_mfma_f32_16x16x32_bf16(
              vf[dt], pf[qt], Of[dt][qt], 0, 0, 0);
    }
  }

  // reduce lsum across the 4 quads holding the same q-column
#pragma unroll
  for (int qt = 0; qt < 4; ++qt) {
    lsum[qt] += __shfl_xor(lsum[qt], 16);
    lsum[qt] += __shfl_xor(lsum[qt], 32);
  }

  // epilogue: O^T lane holds 4 consecutive d (quad*4+reg) for q=l16
#pragma unroll
  for (int qt = 0; qt < 4; ++qt) {
    const float inv = 1.f / lsum[qt];
    const size_t token = (size_t)nb * SL + q0 + qt * 16 + l16;
#pragma unroll
    for (int dt = 0; dt < 4; ++dt) {
      uint2 u;
      u.x = packbf(Of[dt][qt][0] * inv, Of[dt][qt][1] * inv);
      u.y = packbf(Of[dt][qt][2] * inv, Of[dt][qt][3] * inv);
      *(uint2*)(att + token * EMB + h * DH + dt * 16 + quad * 4) = u;
    }
  }
}

// ---------------------------------------------------------------------------
// Kernel 3a: Wf fp32 -> bf16
// ---------------------------------------------------------------------------
__global__ __launch_bounds__(256) void wf_cvt(const float* __restrict__ Wf,
                                              ushort* __restrict__ o) {
  const int i = blockIdx.x * 256 + threadIdx.x;
  float4 f = ((const float4*)Wf)[i];
  uint2 u;
  u.x = packbf(f.x, f.y);
  u.y = packbf(f.z, f.w);
  ((uint2*)o)[i] = u;
}

// ---------------------------------------------------------------------------
// Kernel 3b: final GEMM (m97 structure, unchanged).
// ---------------------------------------------------------------------------
#define GBK 64
__global__ __launch_bounds__(256) void final_gemm_mfma(
    const ushort* __restrict__ A, const ushort* __restrict__ Bt,
    const float* __restrict__ bias, float* __restrict__ C) {
  __shared__ alignas(16) ushort sA[128 * GBK];
  __shared__ alignas(16) ushort sB[128 * GBK];
  const int t = threadIdx.x;
  const int wid = t >> 6, lane = t & 63, quad = lane >> 4, l16 = lane & 15;
  const int n0 = blockIdx.x * 128, m0 = blockIdx.y * 128;
  const int wm = (wid & 1) * 64, wn = (wid >> 1) * 64;

  float4v acc[4][4];
#pragma unroll
  for (int i = 0; i < 4; ++i)
#pragma unroll
    for (int j = 0; j < 4; ++j) acc[i][j] = (float4v){0.f, 0.f, 0.f, 0.f};

  const int arow = lane >> 3;
  const int acol = (lane & 7) * 8;

  for (int k0 = 0; k0 < EMB; k0 += GBK) {
    __syncthreads();
#pragma unroll
    for (int seg = 0; seg < 4; ++seg) {
      const int r = wid * 32 + seg * 8;
      __builtin_amdgcn_global_load_lds(
          (AS1 const void*)(A + (size_t)(m0 + r + arow) * EMB + k0 + acol),
          (AS3 void*)&sA[r * GBK], 16, 0, 0);
      __builtin_amdgcn_global_load_lds(
          (AS1 const void*)(Bt + (size_t)(n0 + r + arow) * EMB + k0 + acol),
          (AS3 void*)&sB[r * GBK], 16, 0, 0);
    }
    __syncthreads();
#pragma unroll
    for (int kk = 0; kk < GBK; kk += 32) {
      short8 af[4], bfr[4];
#pragma unroll
      for (int i = 0; i < 4; ++i)
        af[i] = *(const short8*)&sA[(wm + i * 16 + l16) * GBK + kk + quad * 8];
#pragma unroll
      for (int j = 0; j < 4; ++j)
        bfr[j] = *(const short8*)&sB[(wn + j * 16 + l16) * GBK + kk + quad * 8];
#pragma unroll
      for (int i = 0; i < 4; ++i)
#pragma unroll
        for (int j = 0; j < 4; ++j)
          acc[i][j] = __builtin_amdgcn_mfma_f32_16x16x32_bf16(af[i], bfr[j],
                                                              acc[i][j], 0, 0, 0);
    }
  }

  float bv[4];
#pragma unroll
  for (int j = 0; j < 4; ++j) bv[j] = bias[n0 + wn + j * 16 + l16];
#pragma unroll
  for (int i = 0; i < 4; ++i)
#pragma unroll
    for (int j = 0; j < 4; ++j)
#pragma unroll
      for (int r = 0; r < 4; ++r)
        C[(size_t)(m0 + wm + i * 16 + quad * 4 + r) * EMB + n0 + wn + j * 16 +
          l16] = acc[i][j][r] + bv[j];
}

extern "C" void kernel_launch(void* const* d_in, const int* in_sizes, int n_in,
                              void* d_out, int out_size, void* d_ws,
                              size_t ws_size, hipStream_t stream) {
  const float* values  = (const float*)d_in[0];
  const float* keys    = (const float*)d_in[1];
  const float* queries = (const float*)d_in[2];
  const int*   mask    = (const int*)d_in[3];
  const float* Wv = (const float*)d_in[4];
  const float* Wk = (const float*)d_in[5];
  const float* Wq = (const float*)d_in[6];
  const float* Wf = (const float*)d_in[7];
  const float* bfv = (const float*)d_in[8];
  float* out = (float*)d_out;

  ushort* ws = (ushort*)d_ws;
  ushort* q_ws = ws;
  ushort* k_ws = ws + (size_t)16777216;
  ushort* v_ws = ws + (size_t)33554432;
  ushort* a_ws = ws + (size_t)50331648;
  ushort* wf_bf = q_ws;  // q region dead after attn; stream-ordered reuse

  qkv_proj_mfma<<<dim3(NTOK / 256, NH, 3), 256, 0, stream>>>(
      queries, keys, values, Wq, Wk, Wv, q_ws, k_ws, v_ws);
  attn_win_mfma<<<NB * NW * NH, 256, 0, stream>>>(q_ws, k_ws, v_ws, mask, a_ws);
  wf_cvt<<<1024, 256, 0, stream>>>(Wf, wf_bf);
  final_gemm_mfma<<<dim3(EMB / 128, NTOK / 128), 256, 0, stream>>>(a_ws, wf_bf,
                                                                   bfv, out);
}

// Round 5
// 426.637 us; speedup vs baseline: 1.0921x; 1.0921x over previous
//
#include <hip/hip_runtime.h>
#include <hip/hip_bf16.h>
#include <stdint.h>

typedef unsigned int uint;
typedef unsigned short ushort;

#define NB 4
#define SL 4096
#define EMB 1024
#define NH 16
#define DH 64
#define WIN 256
#define OVL 32
#define NW 16
#define NTOK (NB * SL)

typedef __attribute__((ext_vector_type(8))) short short8;   // 8 bf16 = 4 VGPR
typedef __attribute__((ext_vector_type(4))) float float4v;  // 4 fp32 acc

#define AS1 __attribute__((address_space(1)))
#define AS3 __attribute__((address_space(3)))

// bf16 helpers
__device__ __forceinline__ float bf2f(ushort s) { return __uint_as_float((uint)s << 16); }
__device__ __forceinline__ ushort f2bf(float x) {  // round-to-nearest-even
  uint u = __float_as_uint(x);
  u += 0x7fffu + ((u >> 16) & 1u);
  return (ushort)(u >> 16);
}
__device__ __forceinline__ uint packbf(float a, float b) {
  return (uint)f2bf(a) | ((uint)f2bf(b) << 16);
}

// ---------------------------------------------------------------------------
// Kernel 1: MFMA QKV projection. Grid (16 heads FASTEST, 64 token-tiles, 3
// proj) so the 16 head-blocks sharing a token tile are dispatched together
// (single L3 fetch of the tile).
// q,k outputs: [n][H][L][d]. v output: TRANSPOSED [n][H][d][L] so attention
// can stage V^T with direct 16B loads (operand-swapped MFMA: A=x, B=W ->
// C rows=tok: 4 consecutive tokens pack per b64 LDS store; then 128B
// contiguous global stores).
// ---------------------------------------------------------------------------
__global__ __launch_bounds__(256) void qkv_proj_mfma(
    const float* __restrict__ qin, const float* __restrict__ kin,
    const float* __restrict__ vin,
    const float* __restrict__ Wq, const float* __restrict__ Wk,
    const float* __restrict__ Wv,
    ushort* __restrict__ qo, ushort* __restrict__ ko, ushort* __restrict__ vo) {
  __shared__ alignas(16) ushort smem[256 * 72 + 64 * 72];
  ushort* sx = smem;                // x tile [tok][d] stride 72; later reused
  ushort* sw = smem + 256 * 72;     // W [e][d] stride 72
  ushort* sxT = smem;               // v-path out [e][tok] stride 264 (overlay)

  const int t = threadIdx.x;
  const int wid = t >> 6, lane = t & 63, quad = lane >> 4, l16 = lane & 15;
  const int p = blockIdx.z, h = blockIdx.x;
  const int tok0 = blockIdx.y * 256;
  const int nb = tok0 >> 12, l0 = tok0 & 4095;

  const float* src = (p == 0) ? qin : ((p == 1) ? kin : vin);
  const float* W   = (p == 0) ? Wq  : ((p == 1) ? Wk  : Wv);
  ushort* dst      = (p == 0) ? qo  : ((p == 1) ? ko  : vo);

  // stage W: 64x64 fp32 -> bf16, stride 72
  for (int i = t; i < 1024; i += 256) {
    int e = i >> 4, c4 = i & 15;
    float4 f = *(const float4*)(W + e * 64 + c4 * 4);
    uint2 u;
    u.x = packbf(f.x, f.y);
    u.y = packbf(f.z, f.w);
    *(uint2*)&sw[e * 72 + c4 * 4] = u;
  }
  // stage x tile: 256 tok x 64 d
  for (int i = t; i < 4096; i += 256) {
    int tok = i >> 4, c4 = i & 15;
    float4 f = *(const float4*)(src + (size_t)(tok0 + tok) * EMB + h * DH + c4 * 4);
    uint2 u;
    u.x = packbf(f.x, f.y);
    u.y = packbf(f.z, f.w);
    *(uint2*)&sx[tok * 72 + c4 * 4] = u;
  }
  __syncthreads();

  // fragments (registers; survive the LDS overlay below)
  short8 wfr[4][2], xfr[4][2];
#pragma unroll
  for (int et = 0; et < 4; ++et)
#pragma unroll
    for (int kh = 0; kh < 2; ++kh)
      wfr[et][kh] = *(const short8*)&sw[(et * 16 + l16) * 72 + kh * 32 + quad * 8];
#pragma unroll
  for (int tt = 0; tt < 4; ++tt)
#pragma unroll
    for (int kh = 0; kh < 2; ++kh)
      xfr[tt][kh] = *(const short8*)&sx[(wid * 64 + tt * 16 + l16) * 72 + kh * 32 + quad * 8];

  float4v acc[4][4];
#pragma unroll
  for (int i = 0; i < 4; ++i)
#pragma unroll
    for (int j = 0; j < 4; ++j) acc[i][j] = (float4v){0.f, 0.f, 0.f, 0.f};

  if (p != 2) {
    // D[e][tok]: A=W (m=e), B=x (n=tok)
#pragma unroll
    for (int kh = 0; kh < 2; ++kh)
#pragma unroll
      for (int et = 0; et < 4; ++et)
#pragma unroll
        for (int tt = 0; tt < 4; ++tt)
          acc[et][tt] = __builtin_amdgcn_mfma_f32_16x16x32_bf16(
              wfr[et][kh], xfr[tt][kh], acc[et][tt], 0, 0, 0);
    __syncthreads();
    // lane: col=tok=l16, rows e=et*16+quad*4+reg -> pack 4 e per b64
#pragma unroll
    for (int et = 0; et < 4; ++et)
#pragma unroll
      for (int tt = 0; tt < 4; ++tt) {
        uint2 u;
        u.x = packbf(acc[et][tt][0], acc[et][tt][1]);
        u.y = packbf(acc[et][tt][2], acc[et][tt][3]);
        *(uint2*)&sx[(wid * 64 + tt * 16 + l16) * 72 + et * 16 + quad * 4] = u;
      }
    __syncthreads();
    // thread t owns token tok0+t: 128B contiguous row
    uint4* orow = (uint4*)(dst + ((size_t)(nb * NH + h) * SL + l0 + t) * DH);
#pragma unroll
    for (int j = 0; j < 8; ++j) orow[j] = *(const uint4*)&sx[t * 72 + j * 8];
  } else {
    // v: D[tok][e]: A=x (m=tok), B=W (n=e)
#pragma unroll
    for (int kh = 0; kh < 2; ++kh)
#pragma unroll
      for (int tt = 0; tt < 4; ++tt)
#pragma unroll
        for (int et = 0; et < 4; ++et)
          acc[tt][et] = __builtin_amdgcn_mfma_f32_16x16x32_bf16(
              xfr[tt][kh], wfr[et][kh], acc[tt][et], 0, 0, 0);
    __syncthreads();
    // lane: col=e=l16, rows tok=tt*16+quad*4+reg -> pack 4 consecutive TOKENS
    // into sxT[e][tok], stride 264
#pragma unroll
    for (int tt = 0; tt < 4; ++tt)
#pragma unroll
      for (int et = 0; et < 4; ++et) {
        uint2 u;
        u.x = packbf(acc[tt][et][0], acc[tt][et][1]);
        u.y = packbf(acc[tt][et][2], acc[tt][et][3]);
        *(uint2*)&sxT[(et * 16 + l16) * 264 + wid * 64 + tt * 16 + quad * 4] = u;
      }
    __syncthreads();
    // thread t: e = t>>2, 64-token span part = t&3 -> 128B contiguous
    const int e = t >> 2, part = t & 3;
    uint4* orow = (uint4*)(dst + ((size_t)(nb * NH + h) * DH + e) * SL + l0 + part * 64);
    const ushort* srow = &sxT[e * 264 + part * 64];
#pragma unroll
    for (int j = 0; j < 8; ++j) orow[j] = *(const uint4*)&srow[j * 8];
  }
}

// ---------------------------------------------------------------------------
// Kernel 2: S^T-formulation MFMA windowed attention, fixed-max softmax.
// V^T staged directly from transposed v_ws (no scalar LDS transpose).
// Epilogue: O^T -> LDS -> per-thread 128B contiguous token-row stores.
// ---------------------------------------------------------------------------
__global__ __launch_bounds__(256, 3) void attn_win_mfma(
    const ushort* __restrict__ qws, const ushort* __restrict__ kws,
    const ushort* __restrict__ vws, const int* __restrict__ mask,
    ushort* __restrict__ att) {
  __shared__ alignas(16) ushort smem[19456];
  ushort* sk  = smem;            // K chunk [key][d], stride 72 (64*72)
  ushort* svT = smem + 4608;     // V^T chunk [d][key], stride 72 (64*72)
  ushort* sp  = smem + 9216;     // per-wave P [q][key-half], stride 40 (4*2560)
  ushort* sO  = smem;            // epilogue O [q][d], stride 72 (256*72=18432)

  const int t = threadIdx.x;
  const int wid = t >> 6, lane = t & 63, quad = lane >> 4, l16 = lane & 15;
  const int bid = blockIdx.x;
  const int h = bid & 15, w = (bid >> 4) & 15, nb = bid >> 8;
  const size_t headbase = (size_t)(nb * NH + h) * SL;
  const ushort* vT = vws + (size_t)(nb * NH + h) * DH * SL;  // [d][L]
  const int q0 = w * WIN + wid * 64;

  const float CSC = 0.18033688f;  // 0.125 * log2(e)
  float sc[4];
#pragma unroll
  for (int qt = 0; qt < 4; ++qt)
    sc[qt] = mask[nb * SL + q0 + qt * 16 + l16] ? CSC : 0.f;

  // Q fragments (B operand: n=q=l16, k=d)
  short8 qf[4][2];
#pragma unroll
  for (int qt = 0; qt < 4; ++qt)
#pragma unroll
    for (int kd = 0; kd < 2; ++kd)
      qf[qt][kd] = *(const short8*)(qws + (headbase + q0 + qt * 16 + l16) * DH +
                                    kd * 32 + quad * 8);

  float4v Of[4][4];  // [dt][qt]: O^T C-layout row=d, col=q
#pragma unroll
  for (int dt = 0; dt < 4; ++dt)
#pragma unroll
    for (int qt = 0; qt < 4; ++qt) Of[dt][qt] = (float4v){0.f, 0.f, 0.f, 0.f};
  float lsum[4] = {0.f, 0.f, 0.f, 0.f};

  ushort* spw = &sp[wid * 2560];
  const int gk0 = w * WIN - OVL;

  for (int c = 0; c < 5; ++c) {
    __syncthreads();
    const int cbase = gk0 + c * 64;
    // stage K [key][d]: 128B-contiguous per key row (row-level edge guard)
    // and V^T [d][key]: 128B-contiguous per d row (16B-group edge guard)
    for (int s = t; s < 512; s += 256) {
      const int r = s >> 3, c8 = (s & 7) * 8;
      {
        const int gk = cbase + r;
        uint4 kq = make_uint4(0u, 0u, 0u, 0u);
        if ((unsigned)gk < (unsigned)SL)
          kq = *(const uint4*)(kws + (headbase + gk) * DH + c8);
        *(uint4*)&sk[r * 72 + c8] = kq;
      }
      {
        const int gkc = cbase + c8;  // 8-key group: fully in or out of range
        uint4 vq = make_uint4(0u, 0u, 0u, 0u);
        if (gkc >= 0 && gkc + 8 <= SL)
          vq = *(const uint4*)(vT + (size_t)r * SL + gkc);
        *(uint4*)&svT[r * 72 + c8] = vq;
      }
    }
    __syncthreads();

    const bool kmask = (cbase < 0) || (cbase + 64 > SL);

#pragma unroll
    for (int khk = 0; khk < 2; ++khk) {  // 32-key half
      float4v Sf[2][4];
#pragma unroll
      for (int kt = 0; kt < 2; ++kt)
#pragma unroll
        for (int qt = 0; qt < 4; ++qt) Sf[kt][qt] = (float4v){0.f, 0.f, 0.f, 0.f};
#pragma unroll
      for (int kd = 0; kd < 2; ++kd) {
        short8 kf[2];
#pragma unroll
        for (int kt = 0; kt < 2; ++kt)
          kf[kt] = *(const short8*)&sk[(khk * 32 + kt * 16 + l16) * 72 +
                                       kd * 32 + quad * 8];
#pragma unroll
        for (int kt = 0; kt < 2; ++kt)
#pragma unroll
          for (int qt = 0; qt < 4; ++qt)
            Sf[kt][qt] = __builtin_amdgcn_mfma_f32_16x16x32_bf16(
                kf[kt], qf[qt][kd], Sf[kt][qt], 0, 0, 0);
      }

      // p = exp2(s*sc); zero invalid boundary keys; pack b64 -> LDS
#pragma unroll
      for (int kt = 0; kt < 2; ++kt)
#pragma unroll
        for (int qt = 0; qt < 4; ++qt) {
          float p[4];
#pragma unroll
          for (int r = 0; r < 4; ++r) p[r] = exp2f(Sf[kt][qt][r] * sc[qt]);
          if (kmask) {
#pragma unroll
            for (int r = 0; r < 4; ++r) {
              const int gkey = cbase + khk * 32 + kt * 16 + quad * 4 + r;
              if ((unsigned)gkey >= (unsigned)SL) p[r] = 0.f;
            }
          }
          uint2 u;
          u.x = packbf(p[0], p[1]);
          u.y = packbf(p[2], p[3]);
          lsum[qt] += (bf2f((ushort)(u.x & 0xffffu)) + bf2f((ushort)(u.x >> 16))) +
                      (bf2f((ushort)(u.y & 0xffffu)) + bf2f((ushort)(u.y >> 16)));
          *(uint2*)&spw[(qt * 16 + l16) * 40 + kt * 16 + quad * 4] = u;
        }

      // O^T += V^T · P^T  (A=V^T rows d, B=P rows q; k = 32 keys)
      short8 vf[4], pf[4];
#pragma unroll
      for (int dt = 0; dt < 4; ++dt)
        vf[dt] = *(const short8*)&svT[(dt * 16 + l16) * 72 + khk * 32 + quad * 8];
#pragma unroll
      for (int qt = 0; qt < 4; ++qt)
        pf[qt] = *(const short8*)&spw[(qt * 16 + l16) * 40 + quad * 8];
#pragma unroll
      for (int dt = 0; dt < 4; ++dt)
#pragma unroll
        for (int qt = 0; qt < 4; ++qt)
          Of[dt][qt] = __builtin_amdgcn_mfma_f32_16x16x32_bf16(
              vf[dt], pf[qt], Of[dt][qt], 0, 0, 0);
    }
  }

  // reduce lsum across the 4 quads holding the same q-column
#pragma unroll
  for (int qt = 0; qt < 4; ++qt) {
    lsum[qt] += __shfl_xor(lsum[qt], 16);
    lsum[qt] += __shfl_xor(lsum[qt], 32);
  }

  // epilogue: O^T regs -> sO[q][d] (b64 stores) -> 128B/thread global rows
  __syncthreads();  // all waves done with sk/svT/sp
#pragma unroll
  for (int qt = 0; qt < 4; ++qt) {
    const float inv = 1.f / lsum[qt];
#pragma unroll
    for (int dt = 0; dt < 4; ++dt) {
      uint2 u;
      u.x = packbf(Of[dt][qt][0] * inv, Of[dt][qt][1] * inv);
      u.y = packbf(Of[dt][qt][2] * inv, Of[dt][qt][3] * inv);
      *(uint2*)&sO[(wid * 64 + qt * 16 + l16) * 72 + dt * 16 + quad * 4] = u;
    }
  }
  __syncthreads();
  {
    const size_t token = (size_t)nb * SL + w * WIN + t;
    uint4* orow = (uint4*)(att + token * EMB + h * DH);
#pragma unroll
    for (int j = 0; j < 8; ++j) orow[j] = *(const uint4*)&sO[t * 72 + j * 8];
  }
}

// ---------------------------------------------------------------------------
// Kernel 3a: Wf fp32 -> bf16
// ---------------------------------------------------------------------------
__global__ __launch_bounds__(256) void wf_cvt(const float* __restrict__ Wf,
                                              ushort* __restrict__ o) {
  const int i = blockIdx.x * 256 + threadIdx.x;
  float4 f = ((const float4*)Wf)[i];
  uint2 u;
  u.x = packbf(f.x, f.y);
  u.y = packbf(f.z, f.w);
  ((uint2*)o)[i] = u;
}

// ---------------------------------------------------------------------------
// Kernel 3b: final GEMM (m97 structure, unchanged).
// ---------------------------------------------------------------------------
#define GBK 64
__global__ __launch_bounds__(256) void final_gemm_mfma(
    const ushort* __restrict__ A, const ushort* __restrict__ Bt,
    const float* __restrict__ bias, float* __restrict__ C) {
  __shared__ alignas(16) ushort sA[128 * GBK];
  __shared__ alignas(16) ushort sB[128 * GBK];
  const int t = threadIdx.x;
  const int wid = t >> 6, lane = t & 63, quad = lane >> 4, l16 = lane & 15;
  const int n0 = blockIdx.x * 128, m0 = blockIdx.y * 128;
  const int wm = (wid & 1) * 64, wn = (wid >> 1) * 64;

  float4v acc[4][4];
#pragma unroll
  for (int i = 0; i < 4; ++i)
#pragma unroll
    for (int j = 0; j < 4; ++j) acc[i][j] = (float4v){0.f, 0.f, 0.f, 0.f};

  const int arow = lane >> 3;
  const int acol = (lane & 7) * 8;

  for (int k0 = 0; k0 < EMB; k0 += GBK) {
    __syncthreads();
#pragma unroll
    for (int seg = 0; seg < 4; ++seg) {
      const int r = wid * 32 + seg * 8;
      __builtin_amdgcn_global_load_lds(
          (AS1 const void*)(A + (size_t)(m0 + r + arow) * EMB + k0 + acol),
          (AS3 void*)&sA[r * GBK], 16, 0, 0);
      __builtin_amdgcn_global_load_lds(
          (AS1 const void*)(Bt + (size_t)(n0 + r + arow) * EMB + k0 + acol),
          (AS3 void*)&sB[r * GBK], 16, 0, 0);
    }
    __syncthreads();
#pragma unroll
    for (int kk = 0; kk < GBK; kk += 32) {
      short8 af[4], bfr[4];
#pragma unroll
      for (int i = 0; i < 4; ++i)
        af[i] = *(const short8*)&sA[(wm + i * 16 + l16) * GBK + kk + quad * 8];
#pragma unroll
      for (int j = 0; j < 4; ++j)
        bfr[j] = *(const short8*)&sB[(wn + j * 16 + l16) * GBK + kk + quad * 8];
#pragma unroll
      for (int i = 0; i < 4; ++i)
#pragma unroll
        for (int j = 0; j < 4; ++j)
          acc[i][j] = __builtin_amdgcn_mfma_f32_16x16x32_bf16(af[i], bfr[j],
                                                              acc[i][j], 0, 0, 0);
    }
  }

  float bv[4];
#pragma unroll
  for (int j = 0; j < 4; ++j) bv[j] = bias[n0 + wn + j * 16 + l16];
#pragma unroll
  for (int i = 0; i < 4; ++i)
#pragma unroll
    for (int j = 0; j < 4; ++j)
#pragma unroll
      for (int r = 0; r < 4; ++r)
        C[(size_t)(m0 + wm + i * 16 + quad * 4 + r) * EMB + n0 + wn + j * 16 +
          l16] = acc[i][j][r] + bv[j];
}

extern "C" void kernel_launch(void* const* d_in, const int* in_sizes, int n_in,
                              void* d_out, int out_size, void* d_ws,
                              size_t ws_size, hipStream_t stream) {
  const float* values  = (const float*)d_in[0];
  const float* keys    = (const float*)d_in[1];
  const float* queries = (const float*)d_in[2];
  const int*   mask    = (const int*)d_in[3];
  const float* Wv = (const float*)d_in[4];
  const float* Wk = (const float*)d_in[5];
  const float* Wq = (const float*)d_in[6];
  const float* Wf = (const float*)d_in[7];
  const float* bfv = (const float*)d_in[8];
  float* out = (float*)d_out;

  ushort* ws = (ushort*)d_ws;
  ushort* q_ws = ws;
  ushort* k_ws = ws + (size_t)16777216;
  ushort* v_ws = ws + (size_t)33554432;  // layout [n][H][d][L]
  ushort* a_ws = ws + (size_t)50331648;
  ushort* wf_bf = q_ws;  // q region dead after attn; stream-ordered reuse

  qkv_proj_mfma<<<dim3(NH, NTOK / 256, 3), 256, 0, stream>>>(
      queries, keys, values, Wq, Wk, Wv, q_ws, k_ws, v_ws);
  attn_win_mfma<<<NB * NW * NH, 256, 0, stream>>>(q_ws, k_ws, v_ws, mask, a_ws);
  wf_cvt<<<1024, 256, 0, stream>>>(Wf, wf_bf);
  final_gemm_mfma<<<dim3(EMB / 128, NTOK / 128), 256, 0, stream>>>(a_ws, wf_bf,
                                                                   bfv, out);
}